// Round 14
// baseline (50.599 us; speedup 1.0000x reference)
//
#include <hip/hip_runtime.h>
#include <hip/hip_bf16.h>
#include <cstddef>

// ---------------------------------------------------------------------------
// B=16, N=4, S=64, K=50, VD=1024, QD=768, H=512; ROWS = B*N*S = 4096
//   Ev[k_glob][h] = exp2(CEXP*(v[b,k,:] .Wv[h,:] + bv[h]))   (bf16, row-major)
//   Eq[row][h]    = exp2(CEXP*(q[row,:] .Wq[h,:] + bq[h]))   (fp32, row-major)
//   logit[row][k] = sum_h (-2*wl[h]) * rcp(Ev[k][h]*Eq[row][h] + 1)
//     (tanh(x) = 1 - 2/(e^{2x}+1); exp2 factorized into the projection
//      spaces; k-uniform sum_h wl dropped: softmax-invariant; CEXP=2*log2e)
//   out = masked softmax over k (50 boxes)
// Round 14: GEMM tile 64x64 -> 128x64 (wave tile 64x32): 16 MFMA per wave
// per barrier-pair vs 8, LDS-reads/MFMA 1.5 -> 0.75, counted vmcnt(6).
// ---------------------------------------------------------------------------

typedef __attribute__((ext_vector_type(2))) float          f32x2;
typedef __attribute__((ext_vector_type(4))) float          f32x4;
typedef __attribute__((ext_vector_type(8))) short          bfrag;   // 8 bf16
typedef __attribute__((ext_vector_type(2))) unsigned int   u32x2;
typedef __attribute__((ext_vector_type(4))) unsigned short u16x4;

#define SBAR   __builtin_amdgcn_s_barrier()
#define SCHED0 __builtin_amdgcn_sched_barrier(0)

__device__ __forceinline__ void gload16(const void* g, void* l) {
  __builtin_amdgcn_global_load_lds((const __attribute__((address_space(1))) void*)g,
                                   (__attribute__((address_space(3))) void*)l, 16, 0, 0);
}

__device__ __forceinline__ unsigned int cvtpk(float a, float b) {
  unsigned int r;
  asm("v_cvt_pk_bf16_f32 %0, %1, %2" : "=v"(r) : "v"(a), "v"(b));
  return r;   // low16 = bf16(a), high16 = bf16(b)
}

__device__ __forceinline__ float bf2f(unsigned short u) {
  return __uint_as_float((unsigned int)u << 16);
}

template<int CTRL>
__device__ __forceinline__ float dpp_add(float x) {
  int r = __builtin_amdgcn_update_dpp(0, __float_as_int(x), CTRL, 0xF, 0xF, false);
  return x + __int_as_float(r);
}

// ---------------------------------------------------------------------------
// fp32 -> bf16 conversion of v, Wv, q, Wq (one pass, float4 granularity).
// segments (f32x4 units): v 204800 | Wv 131072 | q 786432 | Wq 98304
// ---------------------------------------------------------------------------
__global__ void __launch_bounds__(256) cvt_all(
    const float* __restrict__ v, const float* __restrict__ wv,
    const float* __restrict__ q, const float* __restrict__ wq,
    unsigned short* __restrict__ vb, unsigned short* __restrict__ wvb,
    unsigned short* __restrict__ qb, unsigned short* __restrict__ wqb) {
  const int total = 1220608;
  for (int f = blockIdx.x * 256 + threadIdx.x; f < total; f += gridDim.x * 256) {
    const float* src; unsigned short* dst; int off;
    if (f < 204800)       { src = v;  dst = vb;  off = f; }
    else if (f < 335872)  { src = wv; dst = wvb; off = f - 204800; }
    else if (f < 1122304) { src = q;  dst = qb;  off = f - 335872; }
    else                  { src = wq; dst = wqb; off = f - 1122304; }
    f32x4 x = ((const f32x4*)src)[off];
    u32x2 p; p[0] = cvtpk(x[0], x[1]); p[1] = cvtpk(x[2], x[3]);
    ((u32x2*)dst)[off] = p;
  }
}

// ---------------------------------------------------------------------------
// Fused bf16 GEMM, tile 128(M) x 64(N), BK=64, 4 waves (2x2), wave tile
// 64x32 -> 16 MFMA / 12 ds_read_b128 / 6 gload16 per wave per step.
// global_load_lds width-16 staging, double-buffered LDS, counted vmcnt(6).
//   m in [0,7)   : v-proj  M=800,  Kd=1024 -> Ev  (bf16 out)
//   m in [7,39)  : q-proj  M=4096, Kd=768  -> Eq  (fp32 out)
// LDS swizzle: physical k-chunk p of row r holds logical chunk p^(r&7)
// (pre-swizzled per-lane GLOBAL source; linear LDS dest); frag reads use
// byte ^((row&7)<<4). m-grouped block decode (id%8 == m%8) for XCD L2 reuse.
// Epilogue stores exp2(CEXP*(acc+bias)).
// ---------------------------------------------------------------------------
__global__ void __launch_bounds__(256) gemm_bf16(
    const unsigned short* __restrict__ vb, const unsigned short* __restrict__ qb,
    const unsigned short* __restrict__ wvb, const unsigned short* __restrict__ wqb,
    const float* __restrict__ bv, const float* __restrict__ bq,
    unsigned short* __restrict__ evw, float* __restrict__ qpw) {
  __shared__ unsigned short As[2][128 * 64];   // 16 KB per buf
  __shared__ unsigned short Bs[2][64 * 64];    //  8 KB per buf

  const int id = blockIdx.x;
  const int m  = (id & 7) + ((id >> 6) << 3);   // m-tile index 0..39
  const int nt = (id >> 3) & 7;                 // n-tile index 0..7
  if (m >= 39) return;

  const int t = threadIdx.x;

  const unsigned short* A; const unsigned short* W; const float* bias;
  int M, Kd, m0;
  const bool vpath = (m < 7);
  if (vpath) { A = vb; W = wvb; bias = bv; M = 800;  Kd = 1024; m0 = m * 128; }
  else       { A = qb; W = wqb; bias = bq; M = 4096; Kd = 768;  m0 = (m - 7) * 128; }
  const int n0 = nt * 64;

  const int lane = t & 63;
  const int wave = t >> 6;
  const int wm   = wave >> 1;
  const int wn   = wave & 1;
  const int la   = lane & 15;
  const int lb   = lane >> 4;

  // staging: A = 1024 chunks (4 groups of 256), B = 512 chunks (2 groups).
  // thread t owns chunk (g*256 + t): row = g*32 + (t>>3), phys k-chunk t&7,
  // logical source chunk (t&7)^(row&7)  [(row&7) == ((t>>3)&7) for all g].
  const int row1 = t >> 3;                   // 0..31
  const int p1   = (t & 7) ^ (row1 & 7);

  const unsigned short* srcA[4]; const unsigned short* srcB[2];
#pragma unroll
  for (int g = 0; g < 4; ++g) {
    int gr = m0 + g * 32 + row1; if (gr >= M) gr = M - 1;   // clamp; stores guarded
    srcA[g] = A + (size_t)gr * Kd + p1 * 8;
  }
#pragma unroll
  for (int g = 0; g < 2; ++g)
    srcB[g] = W + (size_t)(n0 + g * 32 + row1) * Kd + p1 * 8;

  // wave-uniform LDS dest bases (HW adds lane*16B), shorts:
  const int dA = wave * 512;   // + g*2048
  const int dB = wave * 512;

  auto STAGE = [&](int buf, int s) {
    const int o = s * 64;
#pragma unroll
    for (int g = 0; g < 4; ++g) gload16(srcA[g] + o, &As[buf][g * 2048 + dA]);
#pragma unroll
    for (int g = 0; g < 2; ++g) gload16(srcB[g] + o, &Bs[buf][g * 2048 + dB]);
  };

  f32x4 acc[4][2] = {};

  auto compute = [&](const unsigned short* sa, const unsigned short* sb) {
    bfrag af[4][2], bf[2][2];
#pragma unroll
    for (int r = 0; r < 4; ++r)
#pragma unroll
      for (int kk = 0; kk < 2; ++kk) {
        int rowa = wm * 64 + r * 16 + la;
        af[r][kk] = *(const bfrag*)((const char*)sa +
                     ((rowa * 128 + kk * 64 + lb * 16) ^ ((rowa & 7) << 4)));
      }
#pragma unroll
    for (int c = 0; c < 2; ++c)
#pragma unroll
      for (int kk = 0; kk < 2; ++kk) {
        int rowb = wn * 32 + c * 16 + la;
        bf[c][kk] = *(const bfrag*)((const char*)sb +
                     ((rowb * 128 + kk * 64 + lb * 16) ^ ((rowb & 7) << 4)));
      }
#pragma unroll
    for (int kk = 0; kk < 2; ++kk)
#pragma unroll
      for (int r = 0; r < 4; ++r)
#pragma unroll
        for (int c = 0; c < 2; ++c)
          acc[r][c] = __builtin_amdgcn_mfma_f32_16x16x32_bf16(af[r][kk], bf[c][kk], acc[r][c], 0, 0, 0);
  };

  const int nsteps = Kd >> 6;   // 16 (v) / 12 (q)
  STAGE(0, 0);
  STAGE(1, 1);
  for (int s = 0; s < nsteps; ++s) {
    // wait for buf[s&1]'s 6 loads; keep the next step's 6 in flight (T4):
    if (s + 1 < nsteps) { asm volatile("s_waitcnt vmcnt(6)" ::: "memory"); }
    else                { asm volatile("s_waitcnt vmcnt(0)" ::: "memory"); }
    SCHED0;
    SBAR; SCHED0;                 // all waves' loads for this buf retired
    compute(As[s & 1], Bs[s & 1]);
    SBAR; SCHED0;                 // all waves done reading buf[s&1]
    if (s + 2 < nsteps) STAGE(s & 1, s + 2);
  }

  const float CEXP = 2.885390081777927f;   // 2*log2(e)
#pragma unroll
  for (int c = 0; c < 2; ++c) {
    int col = n0 + wn * 32 + c * 16 + la;
    float bcol = bias[col];
#pragma unroll
    for (int r = 0; r < 4; ++r) {
      int mbase = m0 + wm * 64 + r * 16 + lb * 4;
#pragma unroll
      for (int e = 0; e < 4; ++e) {
        int mr = mbase + e;
        if (mr < M) {
          float val = __builtin_amdgcn_exp2f((acc[r][c][e] + bcol) * CEXP);
          if (vpath) evw[(size_t)mr * 512 + col] = (unsigned short)cvtpk(val, val);
          else       qpw[(size_t)mr * 512 + col] = val;
        }
      }
    }
  }
}

// ---------------------------------------------------------------------------
// Stage 3 (UNCHANGED from round 12/13): two rows per wave, bf16 Ev in LDS,
// Eq+wl in registers, 5x10 accumulator chunks (no spill), DPP reduce,
// lane=k masked softmax. grid (16,16), 512 thr = 8 waves.
// ---------------------------------------------------------------------------
__global__ void
__attribute__((amdgpu_flat_work_group_size(512, 512), amdgpu_waves_per_eu(4, 4)))
stage3_kernel(
    const unsigned short* __restrict__ ev, const float* __restrict__ qp,
    const float* __restrict__ wl, const int* __restrict__ box_mask,
    float* __restrict__ out) {
  __shared__ unsigned short vpS[50][512];   // 51,200 B (bf16)
  __shared__ float redS[8][64][8];          // 16,384 B  [wave][k][2g + row]

  const int b    = blockIdx.y;
  const int grp  = blockIdx.x;          // 0..15
  const int t    = threadIdx.x;
  const int wv   = t >> 6;              // 0..7
  const int lane = t & 63;
  const int row0 = b * 256 + grp * 16 + wv * 2;

  const float* q0 = qp + (size_t)row0 * 512;
  float eq0[8], eq1[8], wlr[8];
#pragma unroll
  for (int j = 0; j < 2; ++j) {
    f32x4 a = *(const f32x4*)&q0[j * 256 + 4 * lane];
    f32x4 c = *(const f32x4*)&q0[512 + j * 256 + 4 * lane];
    f32x4 w = *(const f32x4*)&wl[j * 256 + 4 * lane];
#pragma unroll
    for (int e = 0; e < 4; ++e) {
      eq0[j * 4 + e] = a[e];
      eq1[j * 4 + e] = c[e];
      wlr[j * 4 + e] = -2.f * w[e];
    }
  }

  // stage Ev[b] (bf16): per-lane source (+lane*8 shorts), uniform dest.
  {
    const unsigned short* src = ev + (size_t)b * 25600 + lane * 8;
#pragma unroll
    for (int i = 0; i < 7; ++i) {
      int kr = i * 8 + wv;
      if (kr < 50) gload16(src + kr * 512, &vpS[kr][0]);
    }
  }
  __syncthreads();

  const int g  = lane >> 4;
  const int li = lane & 15;

#pragma unroll 1
  for (int kc = 0; kc < 5; ++kc) {
    float a0[10], a1[10];
#pragma unroll
    for (int i = 0; i < 10; ++i) { a0[i] = 0.f; a1[i] = 0.f; }

#pragma unroll
    for (int i = 0; i < 10; ++i) {
      const unsigned short* vr = &vpS[kc * 10 + i][0];
      u16x4 va = *(const u16x4*)&vr[4 * lane];
      u16x4 vb2 = *(const u16x4*)&vr[256 + 4 * lane];
#pragma unroll
      for (int e = 0; e < 4; ++e) {
        float evf = bf2f(va[e]);
        a0[i] = fmaf(wlr[e], __builtin_amdgcn_rcpf(fmaf(evf, eq0[e], 1.f)), a0[i]);
        a1[i] = fmaf(wlr[e], __builtin_amdgcn_rcpf(fmaf(evf, eq1[e], 1.f)), a1[i]);
      }
#pragma unroll
      for (int e = 0; e < 4; ++e) {
        float evf = bf2f(vb2[e]);
        a0[i] = fmaf(wlr[4 + e], __builtin_amdgcn_rcpf(fmaf(evf, eq0[4 + e], 1.f)), a0[i]);
        a1[i] = fmaf(wlr[4 + e], __builtin_amdgcn_rcpf(fmaf(evf, eq1[4 + e], 1.f)), a1[i]);
      }
    }

#pragma unroll
    for (int i = 0; i < 10; ++i) {
      int k = kc * 10 + i;
      float s0 = a0[i], s1 = a1[i];
      s0 = dpp_add<0x128>(s0); s0 = dpp_add<0x124>(s0);
      s0 = dpp_add<0x122>(s0); s0 = dpp_add<0x121>(s0);
      s1 = dpp_add<0x128>(s1); s1 = dpp_add<0x124>(s1);
      s1 = dpp_add<0x122>(s1); s1 = dpp_add<0x121>(s1);
      if (li == (k & 15)) {
        f32x2 p; p[0] = s0; p[1] = s1;
        *(f32x2*)&redS[wv][k][g * 2] = p;
      }
    }
  }

  const int k = lane;
  f32x4 ra = *(const f32x4*)&redS[wv][k][0];
  f32x4 rb = *(const f32x4*)&redS[wv][k][4];
  float l0 = (ra[0] + ra[2]) + (rb[0] + rb[2]);
  float l1 = (ra[1] + ra[3]) + (rb[1] + rb[3]);

  int   msk = (k < 50) ? box_mask[b * 50 + k] : 0;
  bool  on  = (k < 50 && msk > 0);
  float L0 = on ? l0 : -1e9f;
  float L1 = on ? l1 : -1e9f;

  float m0 = L0, m1 = L1;
#pragma unroll
  for (int off = 32; off; off >>= 1) {
    m0 = fmaxf(m0, __shfl_xor(m0, off));
    m1 = fmaxf(m1, __shfl_xor(m1, off));
  }
  const float LOG2E = 1.4426950408889634f;
  float e0 = (k < 50) ? __builtin_amdgcn_exp2f((L0 - m0) * LOG2E) : 0.f;
  float e1 = (k < 50) ? __builtin_amdgcn_exp2f((L1 - m1) * LOG2E) : 0.f;
  float s0 = e0, s1 = e1;
#pragma unroll
  for (int off = 32; off; off >>= 1) {
    s0 += __shfl_xor(s0, off);
    s1 += __shfl_xor(s1, off);
  }

  if (k < 50) {
    out[(size_t)row0 * 50 + k]       = e0 / s0;
    out[(size_t)(row0 + 1) * 50 + k] = e1 / s1;
  }
}

// ---------------------------------------------------------------------------
// launch
// ---------------------------------------------------------------------------
extern "C" void kernel_launch(void* const* d_in, const int* in_sizes, int n_in,
                              void* d_out, int out_size, void* d_ws, size_t ws_size,
                              hipStream_t stream) {
  const float* v        = (const float*)d_in[0];
  const float* q        = (const float*)d_in[1];
  const int*   box_mask = (const int*)d_in[2];
  // d_in[3] = tags_attention (unused by reference)
  const float* Wv       = (const float*)d_in[4];
  const float* bv       = (const float*)d_in[5];
  const float* Wq       = (const float*)d_in[6];
  const float* bq       = (const float*)d_in[7];
  const float* Wl       = (const float*)d_in[8];
  // d_in[9] = bl (softmax-invariant, and zero)
  float* out = (float*)d_out;

  char* ws = (char*)d_ws;
  float*          qpw = (float*)(ws);                        // 8,388,608 B (Eq fp32)
  unsigned short* evw = (unsigned short*)(ws + 8388608);     //   819,200 B (Ev bf16)
  unsigned short* vb  = (unsigned short*)(ws + 9207808);     // 1,638,400 B
  unsigned short* qb  = (unsigned short*)(ws + 10846208);    // 6,291,456 B
  unsigned short* wvb = (unsigned short*)(ws + 17137664);    // 1,048,576 B
  unsigned short* wqb = (unsigned short*)(ws + 18186240);    //   786,432 B  (total ~19 MB)

  cvt_all<<<2048, 256, 0, stream>>>(v, Wv, q, Wq, vb, wvb, qb, wqb);
  gemm_bf16<<<dim3(320), 256, 0, stream>>>(vb, qb, wvb, wqb, bv, bq, evw, qpw);
  stage3_kernel<<<dim3(16, 16), 512, 0, stream>>>(evw, qpw, Wl, box_mask, out);
}

// Round 15
// 44.769 us; speedup vs baseline: 1.1302x; 1.1302x over previous
//
#include <hip/hip_runtime.h>
#include <hip/hip_bf16.h>
#include <cstddef>

// ---------------------------------------------------------------------------
// B=16, N=4, S=64, K=50, VD=1024, QD=768, H=512; ROWS = B*N*S = 4096
//   Ev[k_glob][h] = exp2(CEXP*(v[b,k,:] .Wv[h,:] + bv[h]))   (bf16, row-major)
//   Eq[row][h]    = exp2(CEXP*(q[row,:] .Wq[h,:] + bq[h]))   (bf16, row-major)
//   logit[row][k] = sum_h (-2*wl[h]) * rcp(Ev[k][h]*Eq[row][h] + 1)
//     (tanh(x) = 1 - 2/(e^{2x}+1); exp2 factorized into the projection
//      spaces; k-uniform sum_h wl dropped: softmax-invariant; CEXP=2*log2e)
//   out = masked softmax over k (50 boxes)
// Round 15: revert to r13 GEMM (64x64, 640 blocks — r14's 128x64/312-block
// tile lost to CU load-imbalance); Eq now bf16 (halves gemm writes + stage3
// Eq loads; Ev-bf16 already proven absmax-neutral).
// ---------------------------------------------------------------------------

typedef __attribute__((ext_vector_type(2))) float          f32x2;
typedef __attribute__((ext_vector_type(4))) float          f32x4;
typedef __attribute__((ext_vector_type(8))) short          bfrag;   // 8 bf16
typedef __attribute__((ext_vector_type(2))) unsigned int   u32x2;
typedef __attribute__((ext_vector_type(4))) unsigned short u16x4;

#define SBAR   __builtin_amdgcn_s_barrier()
#define SCHED0 __builtin_amdgcn_sched_barrier(0)

__device__ __forceinline__ void gload16(const void* g, void* l) {
  __builtin_amdgcn_global_load_lds((const __attribute__((address_space(1))) void*)g,
                                   (__attribute__((address_space(3))) void*)l, 16, 0, 0);
}

__device__ __forceinline__ unsigned int cvtpk(float a, float b) {
  unsigned int r;
  asm("v_cvt_pk_bf16_f32 %0, %1, %2" : "=v"(r) : "v"(a), "v"(b));
  return r;   // low16 = bf16(a), high16 = bf16(b)
}

__device__ __forceinline__ float bf2f(unsigned short u) {
  return __uint_as_float((unsigned int)u << 16);
}

template<int CTRL>
__device__ __forceinline__ float dpp_add(float x) {
  int r = __builtin_amdgcn_update_dpp(0, __float_as_int(x), CTRL, 0xF, 0xF, false);
  return x + __int_as_float(r);
}

// ---------------------------------------------------------------------------
// fp32 -> bf16 conversion of v, Wv, q, Wq (one pass, float4 granularity).
// segments (f32x4 units): v 204800 | Wv 131072 | q 786432 | Wq 98304
// ---------------------------------------------------------------------------
__global__ void __launch_bounds__(256) cvt_all(
    const float* __restrict__ v, const float* __restrict__ wv,
    const float* __restrict__ q, const float* __restrict__ wq,
    unsigned short* __restrict__ vb, unsigned short* __restrict__ wvb,
    unsigned short* __restrict__ qb, unsigned short* __restrict__ wqb) {
  const int total = 1220608;
  for (int f = blockIdx.x * 256 + threadIdx.x; f < total; f += gridDim.x * 256) {
    const float* src; unsigned short* dst; int off;
    if (f < 204800)       { src = v;  dst = vb;  off = f; }
    else if (f < 335872)  { src = wv; dst = wvb; off = f - 204800; }
    else if (f < 1122304) { src = q;  dst = qb;  off = f - 335872; }
    else                  { src = wq; dst = wqb; off = f - 1122304; }
    f32x4 x = ((const f32x4*)src)[off];
    u32x2 p; p[0] = cvtpk(x[0], x[1]); p[1] = cvtpk(x[2], x[3]);
    ((u32x2*)dst)[off] = p;
  }
}

// ---------------------------------------------------------------------------
// Fused bf16 GEMM (r13 structure): tile 64x64, BK=64, 4 waves (2x2), wave
// tile 32x32. global_load_lds width-16 staging, double-buffered LDS,
// counted vmcnt(4) (next step's 4 loads stay in flight across barriers).
//   m in [0,13)  : v-proj  M=800,  Kd=1024 -> Ev  (bf16 out)
//   m in [13,77) : q-proj  M=4096, Kd=768  -> Eq  (bf16 out)
// LDS swizzle: physical k-chunk p of row r holds logical chunk p^(r&7)
// (pre-swizzled per-lane GLOBAL source; linear LDS dest); frag reads use
// byte ^((row&7)<<4). m-grouped block decode (id%8 == m%8) for XCD L2 reuse.
// Epilogue stores bf16 exp2(CEXP*(acc+bias)).
// ---------------------------------------------------------------------------
__global__ void __launch_bounds__(256) gemm_bf16(
    const unsigned short* __restrict__ vb, const unsigned short* __restrict__ qb,
    const unsigned short* __restrict__ wvb, const unsigned short* __restrict__ wqb,
    const float* __restrict__ bv, const float* __restrict__ bq,
    unsigned short* __restrict__ evw, unsigned short* __restrict__ qpw) {
  __shared__ unsigned short As[2][64 * 64];   // 8 KB per buf
  __shared__ unsigned short Bs[2][64 * 64];

  const int id = blockIdx.x;
  const int m  = (id & 7) + ((id >> 6) << 3);   // m-tile index
  const int nt = (id >> 3) & 7;                 // n-tile index
  if (m >= 77) return;

  const int t = threadIdx.x;

  const unsigned short* A; const unsigned short* W; const float* bias;
  int M, Kd, m0;
  const bool vpath = (m < 13);
  if (vpath) { A = vb; W = wvb; bias = bv; M = 800;  Kd = 1024; m0 = m * 64; }
  else       { A = qb; W = wqb; bias = bq; M = 4096; Kd = 768;  m0 = (m - 13) * 64; }
  const int n0 = nt * 64;

  const int lane = t & 63;
  const int wave = t >> 6;
  const int wm   = wave >> 1;
  const int wn   = wave & 1;
  const int la   = lane & 15;
  const int lb   = lane >> 4;

  // staging: 512 16B-chunks per matrix per step; thread owns chunks t, t+256.
  // chunk c: row = c>>3 (0..63), physical k-chunk p = c&7; source = logical
  // chunk p^(row&7)  (pre-swizzled source, linear LDS dest).
  const int row1 = t >> 3;                   // 0..31  (chunk t)
  const int p1   = (t & 7) ^ (row1 & 7);     // row2 = row1+32 has same (row&7)
  int grA1 = m0 + row1;      if (grA1 >= M) grA1 = M - 1;   // clamp; stores guarded
  int grA2 = m0 + row1 + 32; if (grA2 >= M) grA2 = M - 1;
  const unsigned short* srcA1 = A + (size_t)grA1 * Kd + p1 * 8;
  const unsigned short* srcA2 = A + (size_t)grA2 * Kd + p1 * 8;
  const unsigned short* srcB1 = W + (size_t)(n0 + row1) * Kd + p1 * 8;
  const unsigned short* srcB2 = W + (size_t)(n0 + row1 + 32) * Kd + p1 * 8;

  // wave-uniform LDS dest bases (HW adds lane*16B): chunks [w*64, w*64+64)
  // at shorts w*512; chunks [256+w*64, ...) at shorts 2048 + w*512.
  const int d1 = wave * 512;
  const int d2 = 2048 + wave * 512;

  auto STAGE = [&](int buf, int s) {
    const int o = s * 64;
    gload16(srcA1 + o, &As[buf][d1]);
    gload16(srcA2 + o, &As[buf][d2]);
    gload16(srcB1 + o, &Bs[buf][d1]);
    gload16(srcB2 + o, &Bs[buf][d2]);
  };

  f32x4 acc[2][2] = {};

  auto compute = [&](const unsigned short* sa, const unsigned short* sb) {
    bfrag af[2][2], bf[2][2];
#pragma unroll
    for (int r = 0; r < 2; ++r)
#pragma unroll
      for (int kk = 0; kk < 2; ++kk) {
        int rowa = wm * 32 + r * 16 + la;
        af[r][kk] = *(const bfrag*)((const char*)sa +
                     ((rowa * 128 + kk * 64 + lb * 16) ^ ((rowa & 7) << 4)));
        int rowb = wn * 32 + r * 16 + la;
        bf[r][kk] = *(const bfrag*)((const char*)sb +
                     ((rowb * 128 + kk * 64 + lb * 16) ^ ((rowb & 7) << 4)));
      }
#pragma unroll
    for (int kk = 0; kk < 2; ++kk)
#pragma unroll
      for (int r = 0; r < 2; ++r)
#pragma unroll
        for (int c = 0; c < 2; ++c)
          acc[r][c] = __builtin_amdgcn_mfma_f32_16x16x32_bf16(af[r][kk], bf[c][kk], acc[r][c], 0, 0, 0);
  };

  const int nsteps = Kd >> 6;   // 16 (v) / 12 (q)
  STAGE(0, 0);
  STAGE(1, 1);
  for (int s = 0; s < nsteps; ++s) {
    // wait for buf[s&1]'s 4 loads; keep the next step's 4 in flight (T4):
    if (s + 1 < nsteps) { asm volatile("s_waitcnt vmcnt(4)" ::: "memory"); }
    else                { asm volatile("s_waitcnt vmcnt(0)" ::: "memory"); }
    SCHED0;
    SBAR; SCHED0;                 // all waves' loads for this buf retired
    compute(As[s & 1], Bs[s & 1]);
    SBAR; SCHED0;                 // all waves done reading buf[s&1]
    if (s + 2 < nsteps) STAGE(s & 1, s + 2);
  }

  const float CEXP = 2.885390081777927f;   // 2*log2(e)
  unsigned short* C = vpath ? evw : qpw;
#pragma unroll
  for (int c = 0; c < 2; ++c) {
    int col = n0 + wn * 32 + c * 16 + la;
    float bcol = bias[col];
#pragma unroll
    for (int r = 0; r < 2; ++r) {
      int mbase = m0 + wm * 32 + r * 16 + lb * 4;
#pragma unroll
      for (int e = 0; e < 4; ++e) {
        int mr = mbase + e;
        if (mr < M) {
          float val = __builtin_amdgcn_exp2f((acc[r][c][e] + bcol) * CEXP);
          C[(size_t)mr * 512 + col] = (unsigned short)cvtpk(val, val);
        }
      }
    }
  }
}

// ---------------------------------------------------------------------------
// Stage 3: two rows per wave, bf16 Ev in LDS, bf16 Eq + wl in registers,
// 5x10 accumulator chunks (no spill), DPP reduce, lane=k masked softmax.
// grid (16,16), 512 thr = 8 waves. waves_per_eu(4,4) pins 128-VGPR budget.
// ---------------------------------------------------------------------------
__global__ void
__attribute__((amdgpu_flat_work_group_size(512, 512), amdgpu_waves_per_eu(4, 4)))
stage3_kernel(
    const unsigned short* __restrict__ ev, const unsigned short* __restrict__ qp,
    const float* __restrict__ wl, const int* __restrict__ box_mask,
    float* __restrict__ out) {
  __shared__ unsigned short vpS[50][512];   // 51,200 B (bf16)
  __shared__ float redS[8][64][8];          // 16,384 B  [wave][k][2g + row]

  const int b    = blockIdx.y;
  const int grp  = blockIdx.x;          // 0..15
  const int t    = threadIdx.x;
  const int wv   = t >> 6;              // 0..7
  const int lane = t & 63;
  const int row0 = b * 256 + grp * 16 + wv * 2;

  // Eq (2 rows, bf16) + wl register slices (fold -2 into wl):
  // h = 256j + 4*lane + e
  const unsigned short* q0 = qp + (size_t)row0 * 512;
  float eq0[8], eq1[8], wlr[8];
#pragma unroll
  for (int j = 0; j < 2; ++j) {
    u16x4 a = *(const u16x4*)&q0[j * 256 + 4 * lane];
    u16x4 c = *(const u16x4*)&q0[512 + j * 256 + 4 * lane];
    f32x4 w = *(const f32x4*)&wl[j * 256 + 4 * lane];
#pragma unroll
    for (int e = 0; e < 4; ++e) {
      eq0[j * 4 + e] = bf2f(a[e]);
      eq1[j * 4 + e] = bf2f(c[e]);
      wlr[j * 4 + e] = -2.f * w[e];
    }
  }

  // stage Ev[b] (bf16): per-lane source (+lane*8 shorts), uniform dest.
  {
    const unsigned short* src = ev + (size_t)b * 25600 + lane * 8;
#pragma unroll
    for (int i = 0; i < 7; ++i) {
      int kr = i * 8 + wv;
      if (kr < 50) gload16(src + kr * 512, &vpS[kr][0]);
    }
  }
  __syncthreads();

  const int g  = lane >> 4;
  const int li = lane & 15;

#pragma unroll 1
  for (int kc = 0; kc < 5; ++kc) {
    float a0[10], a1[10];
#pragma unroll
    for (int i = 0; i < 10; ++i) { a0[i] = 0.f; a1[i] = 0.f; }

#pragma unroll
    for (int i = 0; i < 10; ++i) {
      const unsigned short* vr = &vpS[kc * 10 + i][0];
      u16x4 va = *(const u16x4*)&vr[4 * lane];
      u16x4 vb2 = *(const u16x4*)&vr[256 + 4 * lane];
#pragma unroll
      for (int e = 0; e < 4; ++e) {
        float evf = bf2f(va[e]);
        a0[i] = fmaf(wlr[e], __builtin_amdgcn_rcpf(fmaf(evf, eq0[e], 1.f)), a0[i]);
        a1[i] = fmaf(wlr[e], __builtin_amdgcn_rcpf(fmaf(evf, eq1[e], 1.f)), a1[i]);
      }
#pragma unroll
      for (int e = 0; e < 4; ++e) {
        float evf = bf2f(vb2[e]);
        a0[i] = fmaf(wlr[4 + e], __builtin_amdgcn_rcpf(fmaf(evf, eq0[4 + e], 1.f)), a0[i]);
        a1[i] = fmaf(wlr[4 + e], __builtin_amdgcn_rcpf(fmaf(evf, eq1[4 + e], 1.f)), a1[i]);
      }
    }

#pragma unroll
    for (int i = 0; i < 10; ++i) {
      int k = kc * 10 + i;
      float s0 = a0[i], s1 = a1[i];
      s0 = dpp_add<0x128>(s0); s0 = dpp_add<0x124>(s0);
      s0 = dpp_add<0x122>(s0); s0 = dpp_add<0x121>(s0);
      s1 = dpp_add<0x128>(s1); s1 = dpp_add<0x124>(s1);
      s1 = dpp_add<0x122>(s1); s1 = dpp_add<0x121>(s1);
      if (li == (k & 15)) {
        f32x2 p; p[0] = s0; p[1] = s1;
        *(f32x2*)&redS[wv][k][g * 2] = p;
      }
    }
  }

  const int k = lane;
  f32x4 ra = *(const f32x4*)&redS[wv][k][0];
  f32x4 rb = *(const f32x4*)&redS[wv][k][4];
  float l0 = (ra[0] + ra[2]) + (rb[0] + rb[2]);
  float l1 = (ra[1] + ra[3]) + (rb[1] + rb[3]);

  int   msk = (k < 50) ? box_mask[b * 50 + k] : 0;
  bool  on  = (k < 50 && msk > 0);
  float L0 = on ? l0 : -1e9f;
  float L1 = on ? l1 : -1e9f;

  float m0 = L0, m1 = L1;
#pragma unroll
  for (int off = 32; off; off >>= 1) {
    m0 = fmaxf(m0, __shfl_xor(m0, off));
    m1 = fmaxf(m1, __shfl_xor(m1, off));
  }
  const float LOG2E = 1.4426950408889634f;
  float e0 = (k < 50) ? __builtin_amdgcn_exp2f((L0 - m0) * LOG2E) : 0.f;
  float e1 = (k < 50) ? __builtin_amdgcn_exp2f((L1 - m1) * LOG2E) : 0.f;
  float s0 = e0, s1 = e1;
#pragma unroll
  for (int off = 32; off; off >>= 1) {
    s0 += __shfl_xor(s0, off);
    s1 += __shfl_xor(s1, off);
  }

  if (k < 50) {
    out[(size_t)row0 * 50 + k]       = e0 / s0;
    out[(size_t)(row0 + 1) * 50 + k] = e1 / s1;
  }
}

// ---------------------------------------------------------------------------
// launch
// ---------------------------------------------------------------------------
extern "C" void kernel_launch(void* const* d_in, const int* in_sizes, int n_in,
                              void* d_out, int out_size, void* d_ws, size_t ws_size,
                              hipStream_t stream) {
  const float* v        = (const float*)d_in[0];
  const float* q        = (const float*)d_in[1];
  const int*   box_mask = (const int*)d_in[2];
  // d_in[3] = tags_attention (unused by reference)
  const float* Wv       = (const float*)d_in[4];
  const float* bv       = (const float*)d_in[5];
  const float* Wq       = (const float*)d_in[6];
  const float* bq       = (const float*)d_in[7];
  const float* Wl       = (const float*)d_in[8];
  // d_in[9] = bl (softmax-invariant, and zero)
  float* out = (float*)d_out;

  char* ws = (char*)d_ws;
  unsigned short* qpw = (unsigned short*)(ws);               // 4,194,304 B (Eq bf16)
  unsigned short* evw = (unsigned short*)(ws + 4194304);     //   819,200 B (Ev bf16)
  unsigned short* vb  = (unsigned short*)(ws + 5013504);     // 1,638,400 B
  unsigned short* qb  = (unsigned short*)(ws + 6651904);     // 6,291,456 B
  unsigned short* wvb = (unsigned short*)(ws + 12943360);    // 1,048,576 B
  unsigned short* wqb = (unsigned short*)(ws + 13991936);    //   786,432 B  (total ~14.8 MB)

  cvt_all<<<2048, 256, 0, stream>>>(v, Wv, q, Wq, vb, wvb, qb, wqb);
  gemm_bf16<<<dim3(640), 256, 0, stream>>>(vb, qb, wvb, wqb, bv, bq, evw, qpw);
  stage3_kernel<<<dim3(16, 16), 512, 0, stream>>>(evw, qpw, Wl, box_mask, out);
}